// Round 8
// baseline (3014.615 us; speedup 1.0000x reference)
//
#include <hip/hip_runtime.h>
#include <math.h>

// MoE ViT forward. Wave-private barrier-free bf16-MFMA GEMMs (per-wave 64x32
// tiles, per-wave LDS dbuf, counted vmcnt, depth-2 B-reg prefetch), fp32
// weights staged directly (NT and TN layouts). MFMA attention, wave-per-token LN.
// B=8, S=197, D=768, NH=12, HD=64, E=4, HID=3072, DEPTH=12, NC=1000

#define BB 8
#define SS 197
#define DD 768
#define MT (BB*SS)      // 1576 tokens
#define NPATCH 196
#define MPE (BB*NPATCH) // 1568
#define HHID 3072
#define NEXP 4
#define QKVN 2304
#define SCW 228         // attn score-row stride

typedef __bf16 bf16_t;
typedef bf16_t bf16x4 __attribute__((ext_vector_type(4)));
typedef bf16_t bf16x8 __attribute__((ext_vector_type(8)));
typedef float  f32x4  __attribute__((ext_vector_type(4)));

__device__ __forceinline__ void gload16(const bf16_t* g, bf16_t* l) {
    __builtin_amdgcn_global_load_lds(
        (const __attribute__((address_space(1))) unsigned int*)g,
        (__attribute__((address_space(3))) unsigned int*)l,
        16, 0, 0);
}

__device__ __forceinline__ bf16x8 cvt8(float4 a, float4 b) {
    bf16x8 o;
    o[0]=(bf16_t)a.x; o[1]=(bf16_t)a.y; o[2]=(bf16_t)a.z; o[3]=(bf16_t)a.w;
    o[4]=(bf16_t)b.x; o[5]=(bf16_t)b.y; o[6]=(bf16_t)b.z; o[7]=(bf16_t)b.w;
    return o;
}

template<int N> __device__ __forceinline__ void waitvm();
template<> __device__ __forceinline__ void waitvm<0>()  { asm volatile("s_waitcnt vmcnt(0)"  ::: "memory"); }
template<> __device__ __forceinline__ void waitvm<8>()  { asm volatile("s_waitcnt vmcnt(8)"  ::: "memory"); }
template<> __device__ __forceinline__ void waitvm<12>() { asm volatile("s_waitcnt vmcnt(12)" ::: "memory"); }
template<> __device__ __forceinline__ void waitvm<20>() { asm volatile("s_waitcnt vmcnt(20)" ::: "memory"); }
template<> __device__ __forceinline__ void waitvm<36>() { asm volatile("s_waitcnt vmcnt(36)" ::: "memory"); }

// ---------------- patch gather ----------------
__global__ void gather_patches(const float* __restrict__ x, bf16_t* __restrict__ Xp) {
    int i = blockIdx.x * 256 + threadIdx.x;
    if (i >= MPE * DD) return;
    int k = i % DD;
    int m = i / DD;
    int pw = k & 15, ph = (k >> 4) & 15, cin = k >> 8;
    int px = m % 14, py = (m / 14) % 14, b = m / NPATCH;
    int row = py * 16 + ph, col = px * 16 + pw;
    Xp[i] = (bf16_t)x[((size_t)(b * 3 + cin) * 224 + row) * 224 + col];
}

// ---------------- init: zero cnt + cls rows of h ----------------
__global__ void init_misc(const float* __restrict__ cls, const float* __restrict__ pos,
                          float* __restrict__ h, bf16_t* __restrict__ hb, int* __restrict__ cnt) {
    int i = blockIdx.x * 256 + threadIdx.x;
    if (i < 12*NEXP) cnt[i] = 0;
    if (i < BB * DD) {
        int b = i / DD, d = i % DD;
        float v = cls[d] + pos[d];
        size_t o = (size_t)(b * SS) * DD + d;
        h[o] = v;
        hb[o] = (bf16_t)v;
    }
}

// ---------------- wave-private barrier-free bf16-MFMA GEMM ----------------
// Each wave: 64x32 output tile, private LDS dbuf (BK=32), no __syncthreads.
// C = A[M,K](bf16) @ B^T, B fp32: BL=0 -> [N,K]; BL=1 -> [K,N] in-flight transpose.
// MODE 2: fp32 C += v+bias; 3: gather, bf16 gelu(v+bias); 4: gather, fp32 C += (v+bias)*gv + bf16 mirror;
// MODE 5: bf16 store v+bias; 7: patch-embed row-remapped h/h_bf store of v+bias+pos (pos via gv)
template<int MODE, int BL>
__global__ __launch_bounds__(256) void gemm_wp(
    const bf16_t* A, const bf16_t* __restrict__ A2, int nsplit,
    const float* __restrict__ Bw, const float* __restrict__ bias,
    float* __restrict__ C, bf16_t* __restrict__ Cb,
    const int* __restrict__ cnt, const int* __restrict__ idx,
    const float* __restrict__ gv,
    int M, int N, int K, int mtiles, int ntiles)
{
    constexpr bool GATHER = (MODE == 3 || MODE == 4);
    constexpr int BV = (BL == 0) ? 4 : 16;   // B vmcnt events per K-step

    __shared__ bf16_t AsAll[4][2 * 2048];
    __shared__ bf16_t BsAll[4][2 * 1024];

    int tid = threadIdx.x, lane = tid & 63, w = tid >> 6;
    int tile = blockIdx.x * 4 + w;
    if (tile >= mtiles * ntiles) return;
    int z = blockIdx.z;
    int count = GATHER ? cnt[z] : M;
    int mt = tile / ntiles, nt = tile - mt * ntiles;
    int m0 = mt * 64, n0 = nt * 32;
    if (m0 >= count) return;
    if (n0 >= nsplit) A = A2;
    Bw += (size_t)z * N * K;
    const float* biasz = bias ? (bias + (size_t)z * N) : nullptr;
    bf16_t* AsW = AsAll[w];
    bf16_t* BsW = BsAll[w];

    int mm = m0 + lane; if (mm > count - 1) mm = count - 1;
    int tokv = GATHER ? idx[z * MT + mm] : mm;

    int fr = lane & 15, fs = lane >> 4;

    // A staging: 4 gload16 per K-step, linear LDS dest, pre-swizzled source slot
    int aslot = (lane & 3) ^ ((lane >> 2) & 3);
    const bf16_t* srcA[4];
    #pragma unroll
    for (int gi = 0; gi < 4; gi++) {
        int tok = __shfl(tokv, gi * 16 + (lane >> 2));
        srcA[gi] = A + (size_t)tok * K + aslot * 8;
    }
    int adst = lane * 8;

    // B staging geometry
    int rB = lane >> 1, hB = lane & 1, swzB = rB & 3;             // NT
    int cB = lane & 31, kh = (lane >> 5) * 16, swzC = cB & 3;     // TN
    const float* srcB  = (BL == 0) ? (Bw + (size_t)(n0 + rB) * K + hB * 16) : nullptr;
    const float* srcBT = (BL == 1) ? (Bw + (size_t)kh * N + n0 + cB) : nullptr;

    struct Breg { float4 p0, p1, p2, p3; float v[16]; };
    Breg rE, rO;

    auto bload = [&](Breg& r, int T) {
        if constexpr (BL == 0) {
            const float* s = srcB + (size_t)T * 32;
            r.p0 = *(const float4*)s;       r.p1 = *(const float4*)(s + 4);
            r.p2 = *(const float4*)(s + 8); r.p3 = *(const float4*)(s + 12);
        } else {
            const float* s = srcBT + (size_t)T * 32 * N;
            #pragma unroll
            for (int j = 0; j < 16; j++) r.v[j] = s[(size_t)j * N];
        }
    };
    auto bwrite = [&](Breg& r, int buf) {
        if constexpr (BL == 0) {
            *(bf16x8*)&BsW[buf * 1024 + rB * 32 + (((hB * 2)     ^ swzB) << 3)] = cvt8(r.p0, r.p1);
            *(bf16x8*)&BsW[buf * 1024 + rB * 32 + (((hB * 2 + 1) ^ swzB) << 3)] = cvt8(r.p2, r.p3);
        } else {
            bf16x8 o0, o1;
            #pragma unroll
            for (int j = 0; j < 8; j++) { o0[j] = (bf16_t)r.v[j]; o1[j] = (bf16_t)r.v[j + 8]; }
            int s0 = kh >> 3;
            *(bf16x8*)&BsW[buf * 1024 + cB * 32 + (((s0)     ^ swzC) << 3)] = o0;
            *(bf16x8*)&BsW[buf * 1024 + cB * 32 + (((s0 + 1) ^ swzC) << 3)] = o1;
        }
    };
    auto astage = [&](int T, int buf) {
        #pragma unroll
        for (int gi = 0; gi < 4; gi++)
            gload16(srcA[gi] + (size_t)T * 32, &AsW[buf * 2048 + gi * 512 + adst]);
    };

    f32x4 acc[4][2];
    #pragma unroll
    for (int mi = 0; mi < 4; mi++)
        #pragma unroll
        for (int ni = 0; ni < 2; ni++)
            #pragma unroll
            for (int j = 0; j < 4; j++) acc[mi][ni][j] = 0.f;

    auto step = [&](int buf) {
        bf16x8 af[4], bfr[2];
        #pragma unroll
        for (int mi = 0; mi < 4; mi++) {
            int r = mi * 16 + fr;
            af[mi] = *(bf16x8*)&AsW[buf * 2048 + r * 32 + ((fs ^ (r & 3)) << 3)];
        }
        #pragma unroll
        for (int ni = 0; ni < 2; ni++) {
            int r = ni * 16 + fr;
            bfr[ni] = *(bf16x8*)&BsW[buf * 1024 + r * 32 + ((fs ^ (r & 3)) << 3)];
        }
        #pragma unroll
        for (int mi = 0; mi < 4; mi++)
            #pragma unroll
            for (int ni = 0; ni < 2; ni++)
                acc[mi][ni] = __builtin_amdgcn_mfma_f32_16x16x32_bf16(af[mi], bfr[ni], acc[mi][ni], 0, 0, 0);
    };

    int nk = K >> 5;   // always even (24 or 96)

    // prologue: A(0) issued BEFORE B-reg loads -> FIFO retirement of B fences A
    astage(0, 0);
    __builtin_amdgcn_sched_barrier(0);
    bload(rE, 0);
    bload(rO, 1);
    bwrite(rE, 0);     // implicit reg-wait drains A(0) too (issued earlier)

    for (int t = 0; t < nk; t += 2) {
        // even iter: reads buf0; loads rE <- Breg(t+2); writes B(t+1) from rO
        if (t + 1 < nk) { astage(t + 1, 1); __builtin_amdgcn_sched_barrier(0); }
        if (t + 2 < nk) bload(rE, t + 2);
        if (t + 1 < nk) { if (t + 2 < nk) waitvm<4 + 2 * BV>(); else waitvm<4 + BV>(); }
        else waitvm<0>();
        __builtin_amdgcn_sched_barrier(0);
        step(0);
        if (t + 1 < nk) bwrite(rO, 1);
        __builtin_amdgcn_sched_barrier(0);
        // odd iter
        int t2 = t + 1;
        if (t2 < nk) {
            if (t2 + 1 < nk) { astage(t2 + 1, 0); __builtin_amdgcn_sched_barrier(0); }
            if (t2 + 2 < nk) bload(rO, t2 + 2);
            if (t2 + 1 < nk) { if (t2 + 2 < nk) waitvm<4 + 2 * BV>(); else waitvm<4 + BV>(); }
            else waitvm<0>();
            __builtin_amdgcn_sched_barrier(0);
            step(1);
            if (t2 + 1 < nk) bwrite(rE, 0);
            __builtin_amdgcn_sched_barrier(0);
        }
    }

    // epilogue
    #pragma unroll
    for (int mi = 0; mi < 4; mi++) {
        #pragma unroll
        for (int j = 0; j < 4; j++) {
            int rr = mi * 16 + fs * 4 + j;
            if (m0 + rr >= count) continue;
            int crow = GATHER ? idx[z * MT + m0 + rr] : (m0 + rr);
            #pragma unroll
            for (int ni = 0; ni < 2; ni++) {
                int col = n0 + ni * 16 + fr;
                float v = acc[mi][ni][j];
                if (MODE >= 2) v += biasz[col];
                if (MODE == 2) {
                    C[(size_t)crow * N + col] += v;
                } else if (MODE == 3) {
                    float g = 0.5f * v * (1.0f + tanhf(0.7978845608028654f * (v + 0.044715f * v * v * v)));
                    Cb[(size_t)crow * N + col] = (bf16_t)g;
                } else if (MODE == 4) {
                    float* p = &C[(size_t)crow * N + col];
                    float nv = *p + v * gv[crow];
                    *p = nv;
                    Cb[(size_t)crow * N + col] = (bf16_t)nv;
                } else if (MODE == 5) {
                    Cb[(size_t)crow * N + col] = (bf16_t)v;
                } else if (MODE == 7) {
                    int bb = crow / NPATCH, p = crow - bb * NPATCH;
                    size_t o = ((size_t)(bb * SS + 1 + p)) * DD + col;
                    float vv = v + gv[(size_t)(1 + p) * DD + col];   // gv == pos_embed
                    C[o] = vv;
                    Cb[o] = (bf16_t)vv;
                }
            }
        }
    }
}

// ---------------- LN1: one wave per token, writes qn bf16 ----------------
__global__ __launch_bounds__(256) void ln1_kernel(const float* __restrict__ x,
                                                  const float* __restrict__ g,
                                                  const float* __restrict__ b,
                                                  bf16_t* __restrict__ qn)
{
    int wid = (blockIdx.x * 256 + threadIdx.x) >> 6;
    if (wid >= MT) return;
    int lane = threadIdx.x & 63;
    const float4* xr = (const float4*)(x + (size_t)wid * DD);
    float4 v0 = xr[lane], v1 = xr[lane + 64], v2 = xr[lane + 128];
    float s = v0.x+v0.y+v0.z+v0.w + v1.x+v1.y+v1.z+v1.w + v2.x+v2.y+v2.z+v2.w;
    #pragma unroll
    for (int o = 32; o > 0; o >>= 1) s += __shfl_xor(s, o);
    float mean = s * (1.0f/DD);
    float s2 = 0.f;
    #pragma unroll
    for (int c = 0; c < 3; c++) {
        float4 v = c == 0 ? v0 : (c == 1 ? v1 : v2);
        float dx = v.x-mean, dy = v.y-mean, dz = v.z-mean, dw = v.w-mean;
        s2 += dx*dx + dy*dy + dz*dz + dw*dw;
    }
    #pragma unroll
    for (int o = 32; o > 0; o >>= 1) s2 += __shfl_xor(s2, o);
    float rs = rsqrtf(s2 * (1.0f/DD) + 1e-5f);
    const float4* gr = (const float4*)g;
    const float4* br = (const float4*)b;
    #pragma unroll
    for (int c = 0; c < 3; c++) {
        float4 v = c == 0 ? v0 : (c == 1 ? v1 : v2);
        float4 gg = gr[lane + 64*c], bb = br[lane + 64*c];
        bf16x4 o;
        o[0] = (bf16_t)((v.x - mean) * rs * gg.x + bb.x);
        o[1] = (bf16_t)((v.y - mean) * rs * gg.y + bb.y);
        o[2] = (bf16_t)((v.z - mean) * rs * gg.z + bb.z);
        o[3] = (bf16_t)((v.w - mean) * rs * gg.w + bb.w);
        *(bf16x4*)(qn + (size_t)wid * DD + (lane + 64*c) * 4) = o;
    }
}

// ---------------- LN2 + gate: one wave per token ----------------
__global__ __launch_bounds__(256) void ln2_gate_kernel(const float* __restrict__ x,
                                                       const float* __restrict__ g,
                                                       const float* __restrict__ b,
                                                       const float* __restrict__ gw,
                                                       const float* __restrict__ gb,
                                                       bf16_t* __restrict__ yb,
                                                       float* __restrict__ gv,
                                                       int* __restrict__ cnt,
                                                       int* __restrict__ idxb)
{
    int wid = (blockIdx.x * 256 + threadIdx.x) >> 6;
    if (wid >= MT) return;
    int lane = threadIdx.x & 63;
    const float4* xr = (const float4*)(x + (size_t)wid * DD);
    float4 v0 = xr[lane], v1 = xr[lane + 64], v2 = xr[lane + 128];
    float s = v0.x+v0.y+v0.z+v0.w + v1.x+v1.y+v1.z+v1.w + v2.x+v2.y+v2.z+v2.w;
    #pragma unroll
    for (int o = 32; o > 0; o >>= 1) s += __shfl_xor(s, o);
    float mean = s * (1.0f/DD);
    float s2 = 0.f;
    #pragma unroll
    for (int c = 0; c < 3; c++) {
        float4 v = c == 0 ? v0 : (c == 1 ? v1 : v2);
        float dx = v.x-mean, dy = v.y-mean, dz = v.z-mean, dw = v.w-mean;
        s2 += dx*dx + dy*dy + dz*dz + dw*dw;
    }
    #pragma unroll
    for (int o = 32; o > 0; o >>= 1) s2 += __shfl_xor(s2, o);
    float rs = rsqrtf(s2 * (1.0f/DD) + 1e-5f);
    const float4* gr = (const float4*)g;
    const float4* br = (const float4*)b;
    float p0 = 0.f, p1 = 0.f, p2 = 0.f, p3 = 0.f;
    #pragma unroll
    for (int c = 0; c < 3; c++) {
        float4 v = c == 0 ? v0 : (c == 1 ? v1 : v2);
        float4 gg = gr[lane + 64*c], bb = br[lane + 64*c];
        float y0 = (v.x - mean) * rs * gg.x + bb.x;
        float y1 = (v.y - mean) * rs * gg.y + bb.y;
        float y2 = (v.z - mean) * rs * gg.z + bb.z;
        float y3 = (v.w - mean) * rs * gg.w + bb.w;
        bf16x4 o; o[0]=(bf16_t)y0; o[1]=(bf16_t)y1; o[2]=(bf16_t)y2; o[3]=(bf16_t)y3;
        *(bf16x4*)(yb + (size_t)wid * DD + (lane + 64*c) * 4) = o;
        int off = lane + 64*c;
        float4 w0 = ((const float4*)(gw          ))[off];
        float4 w1v = ((const float4*)(gw +   DD  ))[off];
        float4 w2v = ((const float4*)(gw + 2*DD  ))[off];
        float4 w3v = ((const float4*)(gw + 3*DD  ))[off];
        p0 += y0*w0.x + y1*w0.y + y2*w0.z + y3*w0.w;
        p1 += y0*w1v.x + y1*w1v.y + y2*w1v.z + y3*w1v.w;
        p2 += y0*w2v.x + y1*w2v.y + y2*w2v.z + y3*w2v.w;
        p3 += y0*w3v.x + y1*w3v.y + y2*w3v.z + y3*w3v.w;
    }
    #pragma unroll
    for (int o = 32; o > 0; o >>= 1) {
        p0 += __shfl_xor(p0, o); p1 += __shfl_xor(p1, o);
        p2 += __shfl_xor(p2, o); p3 += __shfl_xor(p3, o);
    }
    if (lane == 0) {
        float l0 = p0 + gb[0], l1 = p1 + gb[1], l2 = p2 + gb[2], l3 = p3 + gb[3];
        int top = 0; float best = l0;
        if (l1 > best) { best = l1; top = 1; }
        if (l2 > best) { best = l2; top = 2; }
        if (l3 > best) { best = l3; top = 3; }
        float Z = __expf(l0-best) + __expf(l1-best) + __expf(l2-best) + __expf(l3-best);
        gv[wid] = 1.0f / Z;
        int pos = atomicAdd(&cnt[top], 1);
        idxb[top * MT + pos] = wid;
    }
}

// ---------------- MFMA attention: block per (q-tile, head, batch); 2 blocks/CU ----------------
__global__ __launch_bounds__(256) void attn_kernel(const bf16_t* __restrict__ qkv,
                                                   bf16_t* __restrict__ ob)
{
    int qt = blockIdx.x, hh = blockIdx.y, b = blockIdx.z;
    __shared__ bf16_t Qs[64 * 64];
    __shared__ bf16_t KV[64 * 68];
    __shared__ float  Sc[64 * SCW];
    __shared__ float  linv[64];

    int tid = threadIdx.x, lane = tid & 63, w = tid >> 6;
    int wm = (w >> 1) * 32, wn = (w & 1) * 32;
    int fr = lane & 15, fs = lane >> 4;

    #pragma unroll
    for (int it = 0; it < 2; it++) {
        int row = 8*(it*4 + w) + (lane >> 3), cc = lane & 7;
        int q = qt*64 + row; if (q > SS-1) q = SS-1;
        const bf16_t* src = qkv + ((size_t)(b*SS + q))*QKVN + hh*64 + ((cc ^ (row & 7)) << 3);
        gload16(src, &Qs[(it*4 + w) * 512]);
    }

    for (int kt = 0; kt < 4; kt++) {
        __syncthreads();
        #pragma unroll
        for (int it = 0; it < 2; it++) {
            int row = 8*(it*4 + w) + (lane >> 3), cc = lane & 7;
            int k = kt*64 + row; if (k > SS-1) k = SS-1;
            const bf16_t* src = qkv + ((size_t)(b*SS + k))*QKVN + 768 + hh*64 + ((cc ^ (row & 7)) << 3);
            gload16(src, &KV[(it*4 + w) * 512]);
        }
        __syncthreads();
        f32x4 acc[2][2];
        #pragma unroll
        for (int mi = 0; mi < 2; mi++)
            #pragma unroll
            for (int ni = 0; ni < 2; ni++)
                #pragma unroll
                for (int j = 0; j < 4; j++) acc[mi][ni][j] = 0.f;
        #pragma unroll
        for (int ks = 0; ks < 2; ks++) {
            bf16x8 af[2], bfr[2];
            #pragma unroll
            for (int mi = 0; mi < 2; mi++) {
                int r = wm + mi * 16 + fr;
                af[mi] = *(bf16x8*)&Qs[r * 64 + (((fs + ks*4) ^ (r & 7)) << 3)];
            }
            #pragma unroll
            for (int ni = 0; ni < 2; ni++) {
                int r = wn + ni * 16 + fr;
                bfr[ni] = *(bf16x8*)&KV[r * 64 + (((fs + ks*4) ^ (r & 7)) << 3)];
            }
            #pragma unroll
            for (int mi = 0; mi < 2; mi++)
                #pragma unroll
                for (int ni = 0; ni < 2; ni++)
                    acc[mi][ni] = __builtin_amdgcn_mfma_f32_16x16x32_bf16(af[mi], bfr[ni], acc[mi][ni], 0, 0, 0);
        }
        #pragma unroll
        for (int mi = 0; mi < 2; mi++)
            #pragma unroll
            for (int j = 0; j < 4; j++) {
                int qr = wm + mi * 16 + fs * 4 + j;
                #pragma unroll
                for (int ni = 0; ni < 2; ni++) {
                    int col = kt*64 + wn + ni * 16 + fr;
                    if (col < SCW) {
                        float v = acc[mi][ni][j] * 0.125f;
                        if (col > SS-1) v = -1e30f;
                        Sc[qr * SCW + col] = v;
                    }
                }
            }
    }
    __syncthreads();

    {
        int row = tid >> 2, c = tid & 3;
        float m = -1e30f;
        for (int i = c; i < SCW; i += 4) m = fmaxf(m, Sc[row * SCW + i]);
        m = fmaxf(m, __shfl_xor(m, 1, 4));
        m = fmaxf(m, __shfl_xor(m, 2, 4));
        float s = 0.f;
        for (int i = c; i < SCW; i += 4) {
            float e = __expf(Sc[row * SCW + i] - m);
            Sc[row * SCW + i] = e;
            s += e;
        }
        s += __shfl_xor(s, 1, 4);
        s += __shfl_xor(s, 2, 4);
        if (c == 0) linv[row] = 1.0f / s;
    }

    f32x4 pv[2][2];
    #pragma unroll
    for (int mi = 0; mi < 2; mi++)
        #pragma unroll
        for (int ni = 0; ni < 2; ni++)
            #pragma unroll
            for (int j = 0; j < 4; j++) pv[mi][ni][j] = 0.f;

    for (int kt = 0; kt < 4; kt++) {
        __syncthreads();
        {
            int s = tid >> 2, c2 = tid & 3;
            int k = kt*64 + s; if (k > SS-1) k = SS-1;
            const bf16_t* vr = qkv + ((size_t)(b*SS + k))*QKVN + 1536 + hh*64;
            bf16x8 v0 = *(const bf16x8*)(vr + c2*16);
            bf16x8 v1 = *(const bf16x8*)(vr + c2*16 + 8);
            #pragma unroll
            for (int j = 0; j < 8; j++) {
                KV[(c2*16 + j) * 68 + s]     = v0[j];
                KV[(c2*16 + 8 + j) * 68 + s] = v1[j];
            }
        }
        __syncthreads();
        #pragma unroll
        for (int ks = 0; ks < 2; ks++) {
            int s0 = kt*64 + ks*32;
            if (s0 > SS-1) continue;
            bf16x8 af[2], bfr[2];
            #pragma unroll
            for (int mi = 0; mi < 2; mi++) {
                int qr = wm + mi * 16 + fr;
                const float* p = &Sc[qr * SCW + s0 + fs * 8];
                af[mi] = cvt8(*(const float4*)p, *(const float4*)(p + 4));
            }
            #pragma unroll
            for (int ni = 0; ni < 2; ni++) {
                int d = wn + ni * 16 + fr;
                bfr[ni] = *(bf16x8*)&KV[d * 68 + ks*32 + fs*8];
            }
            #pragma unroll
            for (int mi = 0; mi < 2; mi++)
                #pragma unroll
                for (int ni = 0; ni < 2; ni++)
                    pv[mi][ni] = __builtin_amdgcn_mfma_f32_16x16x32_bf16(af[mi], bfr[ni], pv[mi][ni], 0, 0, 0);
        }
    }

    #pragma unroll
    for (int mi = 0; mi < 2; mi++)
        #pragma unroll
        for (int j = 0; j < 4; j++) {
            int qr = wm + mi * 16 + fs * 4 + j;
            int q = qt*64 + qr;
            if (q > SS-1) continue;
            float il = linv[qr];
            #pragma unroll
            for (int ni = 0; ni < 2; ni++) {
                int d = wn + ni * 16 + fr;
                ob[((size_t)(b*SS + q))*DD + hh*64 + d] = (bf16_t)(pv[mi][ni][j] * il);
            }
        }
}

// ---------------- classifier head ----------------
__global__ void head_kernel(const float* __restrict__ h, const float* __restrict__ hw,
                            const float* __restrict__ hb, float* __restrict__ out)
{
    int i = blockIdx.x * 256 + threadIdx.x;
    if (i >= BB * 1000) return;
    int b = i & 7, n = i >> 3;
    const float4* hr = (const float4*)(h + (size_t)(b * SS) * DD);
    const float4* wr = (const float4*)(hw + (size_t)n * DD);
    float s = 0.f;
    #pragma unroll 4
    for (int k = 0; k < DD/4; k++) {
        float4 a = hr[k], wv = wr[k];
        s += a.x*wv.x + a.y*wv.y + a.z*wv.z + a.w*wv.w;
    }
    out[b * 1000 + n] = s + hb[n];
}

extern "C" void kernel_launch(void* const* d_in, const int* in_sizes, int n_in,
                              void* d_out, int out_size, void* d_ws, size_t ws_size,
                              hipStream_t stream) {
    const float* x          = (const float*)d_in[0];
    const float* patch_w    = (const float*)d_in[1];
    const float* patch_b    = (const float*)d_in[2];
    const float* cls_token  = (const float*)d_in[3];
    const float* pos_embed  = (const float*)d_in[4];
    const float* ln1_g      = (const float*)d_in[5];
    const float* ln1_b      = (const float*)d_in[6];
    const float* ln2_g      = (const float*)d_in[7];
    const float* ln2_b      = (const float*)d_in[8];
    const float* attn_in_w  = (const float*)d_in[9];
    const float* attn_in_b  = (const float*)d_in[10];
    const float* attn_out_w = (const float*)d_in[11];
    const float* attn_out_b = (const float*)d_in[12];
    const float* gate_w     = (const float*)d_in[13];
    const float* gate_b     = (const float*)d_in[14];
    const float* w1         = (const float*)d_in[15];
    const float* b1         = (const float*)d_in[16];
    const float* w2         = (const float*)d_in[17];
    const float* b2         = (const float*)d_in[18];
    const float* head_w     = (const float*)d_in[19];
    const float* head_b     = (const float*)d_in[20];
    float* out = (float*)d_out;

    char* wsb = (char*)d_ws;
    auto alloc = [&](size_t bytes) { char* p = wsb; wsb += (bytes + 63) & ~63ULL; return p; };
    bf16_t* Xp     = (bf16_t*)alloc((size_t)MPE * DD * 2);
    float*  h      = (float*) alloc((size_t)MT * DD * 4);
    bf16_t* qn_bf  = (bf16_t*)alloc((size_t)MT * DD * 2);
    bf16_t* h_bf   = (bf16_t*)alloc((size_t)MT * DD * 2);
    bf16_t* qkv_bf = (bf16_t*)alloc((size_t)MT * QKVN * 2);
    bf16_t* ob_bf  = (bf16_t*)alloc((size_t)MT * DD * 2);
    bf16_t* yb_bf  = (bf16_t*)alloc((size_t)MT * DD * 2);
    bf16_t* hd_bf  = (bf16_t*)alloc((size_t)MT * HHID * 2);
    float*  gv     = (float*) alloc((size_t)MT * 4);
    int*    cnt    = (int*)   alloc(12 * NEXP * 4);
    int*    idxb   = (int*)   alloc((size_t)12 * NEXP * MT * 4);

    dim3 blk(256);
    const int NOSPLIT = 1 << 30;

    init_misc<<<24, blk, 0, stream>>>(cls_token, pos_embed, h, h_bf, cnt);
    gather_patches<<<(MPE*DD + 255)/256, blk, 0, stream>>>(x, Xp);
    // patch embed -> h rows s>=1 (bias=patch_b, pos via gv slot): 25x24 wave-tiles
    gemm_wp<7,0><<<dim3(150, 1, 1), blk, 0, stream>>>(
        Xp, nullptr, NOSPLIT, patch_w, patch_b, h, h_bf, nullptr, nullptr, pos_embed,
        MPE, DD, DD, 25, 24);

    for (int i = 0; i < 12; i++) {
        const float* aw    = attn_in_w  + (size_t)i * QKVN * DD;
        const float* ow    = attn_out_w + (size_t)i * DD * DD;
        const float* w1l   = w1 + (size_t)i * NEXP * DD * HHID;
        const float* w2l   = w2 + (size_t)i * NEXP * HHID * DD;
        const float* ab    = attn_in_b  + (size_t)i * QKVN;
        const float* obias = attn_out_b + (size_t)i * DD;
        const float* l1g = ln1_g + (size_t)i * DD;
        const float* l1b = ln1_b + (size_t)i * DD;
        const float* l2g = ln2_g + (size_t)i * DD;
        const float* l2b = ln2_b + (size_t)i * DD;
        const float* gw  = gate_w + (size_t)i * NEXP * DD;
        const float* gb  = gate_b + (size_t)i * NEXP;
        const float* b1l = b1 + (size_t)i * NEXP * HHID;
        const float* b2l = b2 + (size_t)i * NEXP * DD;
        int* cnt_i  = cnt  + i * NEXP;
        int* idxb_i = idxb + (size_t)i * NEXP * MT;

        ln1_kernel<<<dim3((MT*64 + 255)/256), blk, 0, stream>>>(h, l1g, l1b, qn_bf);
        // merged q|kv projection: 25x72 wave-tiles; n0<768 -> qn_bf else h_bf
        gemm_wp<5,0><<<dim3(450, 1, 1), blk, 0, stream>>>(
            qn_bf, h_bf, DD, aw, ab, nullptr, qkv_bf, nullptr, nullptr, nullptr,
            MT, QKVN, DD, 25, 72);
        attn_kernel<<<dim3(4, 12, BB), blk, 0, stream>>>(qkv_bf, ob_bf);
        gemm_wp<2,0><<<dim3(150, 1, 1), blk, 0, stream>>>(
            ob_bf, nullptr, NOSPLIT, ow, obias, h, nullptr, nullptr, nullptr, nullptr,
            MT, DD, DD, 25, 24);
        ln2_gate_kernel<<<dim3((MT*64 + 255)/256), blk, 0, stream>>>(
            h, l2g, l2b, gw, gb, yb_bf, gv, cnt_i, idxb_i);
        // moe1: w1[i] fp32 [768,3072] TN; 25x96 wave-tiles per expert
        gemm_wp<3,1><<<dim3(600, 1, NEXP), blk, 0, stream>>>(
            yb_bf, nullptr, NOSPLIT, w1l, b1l, nullptr, hd_bf, cnt_i, idxb_i, nullptr,
            MT, HHID, DD, 25, 96);
        // moe2: w2[i] fp32 [3072,768] TN; 25x24 wave-tiles per expert
        gemm_wp<4,1><<<dim3(150, 1, NEXP), blk, 0, stream>>>(
            hd_bf, nullptr, NOSPLIT, w2l, b2l, h, h_bf, cnt_i, idxb_i, gv,
            MT, DD, HHID, 25, 24);
    }

    head_kernel<<<(BB*1000 + 255)/256, blk, 0, stream>>>(h, head_w, head_b, out);
}

// Round 9
// 2251.853 us; speedup vs baseline: 1.3387x; 1.3387x over previous
//
#include <hip/hip_runtime.h>
#include <math.h>

// MoE ViT forward. R7 base (2-barrier bf16-MFMA GEMM, fp32-B direct staging)
// + XCD-chunked block remap on GEMMs + pre-transposed V for attention PV.
// B=8, S=197, D=768, NH=12, HD=64, E=4, HID=3072, DEPTH=12, NC=1000

#define BB 8
#define SS 197
#define DD 768
#define MT (BB*SS)      // 1576 tokens
#define NPATCH 196
#define MPE (BB*NPATCH) // 1568
#define HHID 3072
#define NEXP 4
#define QKVN 2304
#define SCW 228         // attn score-row stride
#define SPAD 256        // vt column pad

typedef __bf16 bf16_t;
typedef bf16_t bf16x4 __attribute__((ext_vector_type(4)));
typedef bf16_t bf16x8 __attribute__((ext_vector_type(8)));
typedef float  f32x4  __attribute__((ext_vector_type(4)));

__device__ __forceinline__ void gload16(const bf16_t* g, bf16_t* l) {
    __builtin_amdgcn_global_load_lds(
        (const __attribute__((address_space(1))) unsigned int*)g,
        (__attribute__((address_space(3))) unsigned int*)l,
        16, 0, 0);
}

__device__ __forceinline__ bf16x8 cvt8(float4 a, float4 b) {
    bf16x8 o;
    o[0]=(bf16_t)a.x; o[1]=(bf16_t)a.y; o[2]=(bf16_t)a.z; o[3]=(bf16_t)a.w;
    o[4]=(bf16_t)b.x; o[5]=(bf16_t)b.y; o[6]=(bf16_t)b.z; o[7]=(bf16_t)b.w;
    return o;
}

// ---------------- patch gather ----------------
__global__ void gather_patches(const float* __restrict__ x, bf16_t* __restrict__ Xp) {
    int i = blockIdx.x * 256 + threadIdx.x;
    if (i >= MPE * DD) return;
    int k = i % DD;
    int m = i / DD;
    int pw = k & 15, ph = (k >> 4) & 15, cin = k >> 8;
    int px = m % 14, py = (m / 14) % 14, b = m / NPATCH;
    int row = py * 16 + ph, col = px * 16 + pw;
    Xp[i] = (bf16_t)x[((size_t)(b * 3 + cin) * 224 + row) * 224 + col];
}

// ---------------- init: zero cnt + cls rows of h ----------------
__global__ void init_misc(const float* __restrict__ cls, const float* __restrict__ pos,
                          float* __restrict__ h, bf16_t* __restrict__ hb, int* __restrict__ cnt) {
    int i = blockIdx.x * 256 + threadIdx.x;
    if (i < 12*NEXP) cnt[i] = 0;
    if (i < BB * DD) {
        int b = i / DD, d = i % DD;
        float v = cls[d] + pos[d];
        size_t o = (size_t)(b * SS) * DD + d;
        h[o] = v;
        hb[o] = (bf16_t)v;
    }
}

// ---------------- V transpose: vt[b*12+h][d][s] = qkv[b][s][1536+h*64+d] ----------------
__global__ __launch_bounds__(256) void transpose_v(const bf16_t* __restrict__ qkv,
                                                   bf16_t* __restrict__ vt) {
    int sx = blockIdx.x;           // 8 tiles of 32 along s (0..255)
    int dx = blockIdx.y;           // 2 tiles of 32 along d
    int bh = blockIdx.z;           // b*12+h
    int b = bh / 12, hh = bh % 12;
    __shared__ bf16_t t[32][33];
    int tx = threadIdx.x & 31, ty = threadIdx.x >> 5;
    #pragma unroll
    for (int i = 0; i < 4; i++) {
        int s = sx*32 + ty + 8*i;
        bf16_t v = (bf16_t)0.f;
        if (s < SS) v = qkv[((size_t)(b*SS + s))*QKVN + 1536 + hh*64 + dx*32 + tx];
        t[ty + 8*i][tx] = v;
    }
    __syncthreads();
    #pragma unroll
    for (int i = 0; i < 4; i++) {
        int d = dx*32 + ty + 8*i;
        vt[((size_t)(bh*64 + d))*SPAD + sx*32 + tx] = t[tx][ty + 8*i];
    }
}

// ---------------- unified bf16-MFMA GEMM, fp32-B direct staging, XCD-chunked remap ----------------
// C = A[M,K](bf16) @ B^T, B fp32: BL=0 -> [N,K] row-major; BL=1 -> [K,N] (transposed in-flight)
// MODE 2: fp32 C += v+bias; 3: gather, bf16 gelu(v+bias); 4: gather, fp32 C += (v+bias)*gv + bf16 mirror;
// MODE 5: bf16 store v+bias; 7: patch-embed: h/h_bf row-remapped store of v+bias+pos (pos via gv)
template<int BM, int BN, int WM, int WN, int MODE, int BL>
__global__ __launch_bounds__((BM/WM)*(BN/WN)*64) void gemm_bf16(
    const bf16_t* __restrict__ A, const bf16_t* __restrict__ A2, int nsplit,
    const float* __restrict__ Bw,
    const float* __restrict__ bias, float* __restrict__ C, bf16_t* __restrict__ Cb,
    const int* __restrict__ cnt, const int* __restrict__ idx,
    const float* __restrict__ gv, int M, int N, int K, int mtiles, int ntiles)
{
    constexpr int NW  = (BM/WM)*(BN/WN);
    constexpr int NTH = NW * 64;
    constexpr int WNC = BN/WN;
    constexpr int MI  = WM/16;
    constexpr int NI  = WN/16;
    constexpr int IA  = (BM/8)/NW;
    constexpr int BT  = (BN*8)/NTH;      // B staging tasks per thread
    constexpr bool GATHER = (MODE == 3 || MODE == 4);

    // XCD-chunked bijective remap (m204): blocks sharing a B panel (same nt)
    // are contiguous in wg-space (m fastest) -> land on the same XCD's L2.
    int nwg = mtiles * ntiles;
    int orig = blockIdx.x;
    int q8 = nwg >> 3, r8 = nwg & 7, xcd = orig & 7, within = orig >> 3;
    int wg = (xcd < r8 ? xcd * (q8 + 1) : r8 * (q8 + 1) + (xcd - r8) * q8) + within;
    int mt = wg % mtiles, nt = wg / mtiles;

    int z = blockIdx.z;
    int count = GATHER ? cnt[z] : M;
    int m0 = mt * BM;
    if (m0 >= count) return;
    int n0 = nt * BN;
    if (n0 >= nsplit) A = A2;
    Bw += (size_t)z * N * K;
    const float* biasz = bias ? (bias + (size_t)z * N) : nullptr;

    __shared__ bf16_t As[2][BM * 64];
    __shared__ bf16_t Bs[2][BN * 64];
    __shared__ int toks[BM];

    int tid = threadIdx.x, lane = tid & 63, w = tid >> 6;
    if (tid < BM) {
        int mm = m0 + tid;
        if (mm > count - 1) mm = count - 1;
        toks[tid] = GATHER ? idx[z * MT + mm] : mm;
    }
    __syncthreads();

    int wm = (w / WNC) * WM, wn = (w % WNC) * WN;
    int fr = lane & 15, fs = lane >> 4;

    f32x4 acc[MI][NI];
    #pragma unroll
    for (int mi = 0; mi < MI; mi++)
        #pragma unroll
        for (int ni = 0; ni < NI; ni++)
            #pragma unroll
            for (int j = 0; j < 4; j++) acc[mi][ni][j] = 0.f;

    int nk = K >> 6;
    int srow = lane >> 3, scc = lane & 7;

    float4 bA[BT], bB[BT];     // NT staging regs
    float  bt[BT][8];          // TN staging regs

    #define A_STAGE(buf, k0)                                                            \
        {                                                                               \
            _Pragma("unroll")                                                           \
            for (int i = 0; i < IA; i++) {                                              \
                int blk = i*NW + w;                                                     \
                int row = blk*8 + srow;                                                 \
                const bf16_t* s = A + (size_t)toks[row] * K + (k0) + ((scc ^ (row & 7)) << 3); \
                gload16(s, &As[buf][blk * 512]);                                        \
            }                                                                           \
        }

    #define B_LOAD(k0)                                                                  \
        {                                                                               \
            _Pragma("unroll")                                                           \
            for (int i = 0; i < BT; i++) {                                              \
                int task = i*NTH + tid;                                                 \
                if (BL == 0) {                                                          \
                    int row = task >> 3, sl = task & 7;                                 \
                    const float* s = Bw + (size_t)(n0 + row) * K + (k0) + sl*8;         \
                    bA[i] = *(const float4*)s;                                          \
                    bB[i] = *(const float4*)(s + 4);                                    \
                } else {                                                                \
                    int n = task & (BN-1), sl = task / BN;                              \
                    const float* s = Bw + (size_t)((k0) + sl*8) * N + n0 + n;           \
                    _Pragma("unroll")                                                   \
                    for (int j = 0; j < 8; j++) bt[i][j] = s[(size_t)j * N];            \
                }                                                                       \
            }                                                                           \
        }

    #define B_WRITE(buf)                                                                \
        {                                                                               \
            _Pragma("unroll")                                                           \
            for (int i = 0; i < BT; i++) {                                              \
                int task = i*NTH + tid;                                                 \
                int row, sl;                                                            \
                bf16x8 o;                                                               \
                if (BL == 0) {                                                          \
                    row = task >> 3; sl = task & 7;                                     \
                    o = cvt8(bA[i], bB[i]);                                             \
                } else {                                                                \
                    row = task & (BN-1); sl = task / BN;                                \
                    _Pragma("unroll")                                                   \
                    for (int j = 0; j < 8; j++) o[j] = (bf16_t)bt[i][j];                \
                }                                                                       \
                *(bf16x8*)&Bs[buf][row * 64 + ((sl ^ (row & 7)) << 3)] = o;             \
            }                                                                           \
        }

    A_STAGE(0, 0);
    B_LOAD(0);
    B_WRITE(0);
    __syncthreads();
    int cur = 0;
    for (int t = 0; t < nk; t++) {
        if (t + 1 < nk) { A_STAGE(cur ^ 1, (t + 1) << 6); B_LOAD((t + 1) << 6); }
        #pragma unroll
        for (int ks = 0; ks < 2; ks++) {
            bf16x8 af[MI], bfr[NI];
            #pragma unroll
            for (int mi = 0; mi < MI; mi++) {
                int r = wm + mi * 16 + fr;
                af[mi] = *(bf16x8*)&As[cur][r * 64 + (((fs + ks*4) ^ (r & 7)) << 3)];
            }
            #pragma unroll
            for (int ni = 0; ni < NI; ni++) {
                int r = wn + ni * 16 + fr;
                bfr[ni] = *(bf16x8*)&Bs[cur][r * 64 + (((fs + ks*4) ^ (r & 7)) << 3)];
            }
            #pragma unroll
            for (int mi = 0; mi < MI; mi++)
                #pragma unroll
                for (int ni = 0; ni < NI; ni++)
                    acc[mi][ni] = __builtin_amdgcn_mfma_f32_16x16x32_bf16(af[mi], bfr[ni], acc[mi][ni], 0, 0, 0);
        }
        if (t + 1 < nk) B_WRITE(cur ^ 1);
        __syncthreads();
        cur ^= 1;
    }
    #undef A_STAGE
    #undef B_LOAD
    #undef B_WRITE

    #pragma unroll
    for (int mi = 0; mi < MI; mi++) {
        #pragma unroll
        for (int j = 0; j < 4; j++) {
            int rr = wm + mi * 16 + fs * 4 + j;
            if (m0 + rr >= count) continue;
            int crow = toks[rr];
            #pragma unroll
            for (int ni = 0; ni < NI; ni++) {
                int col = n0 + wn + ni * 16 + fr;
                float v = acc[mi][ni][j];
                if (MODE >= 2) v += biasz[col];
                if (MODE == 2) {
                    C[(size_t)crow * N + col] += v;
                } else if (MODE == 3) {
                    float g = 0.5f * v * (1.0f + tanhf(0.7978845608028654f * (v + 0.044715f * v * v * v)));
                    Cb[(size_t)crow * N + col] = (bf16_t)g;
                } else if (MODE == 4) {
                    float* p = &C[(size_t)crow * N + col];
                    float nv = *p + v * gv[crow];
                    *p = nv;
                    Cb[(size_t)crow * N + col] = (bf16_t)nv;
                } else if (MODE == 5) {
                    Cb[(size_t)crow * N + col] = (bf16_t)v;
                } else if (MODE == 7) {
                    int bb = crow / NPATCH, p = crow - bb * NPATCH;
                    size_t o = ((size_t)(bb * SS + 1 + p)) * DD + col;
                    float vv = v + gv[(size_t)(1 + p) * DD + col];   // gv == pos_embed
                    C[o] = vv;
                    Cb[o] = (bf16_t)vv;
                }
            }
        }
    }
}

// ---------------- LN1: one wave per token, writes qn bf16 ----------------
__global__ __launch_bounds__(256) void ln1_kernel(const float* __restrict__ x,
                                                  const float* __restrict__ g,
                                                  const float* __restrict__ b,
                                                  bf16_t* __restrict__ qn)
{
    int wid = (blockIdx.x * 256 + threadIdx.x) >> 6;
    if (wid >= MT) return;
    int lane = threadIdx.x & 63;
    const float4* xr = (const float4*)(x + (size_t)wid * DD);
    float4 v0 = xr[lane], v1 = xr[lane + 64], v2 = xr[lane + 128];
    float s = v0.x+v0.y+v0.z+v0.w + v1.x+v1.y+v1.z+v1.w + v2.x+v2.y+v2.z+v2.w;
    #pragma unroll
    for (int o = 32; o > 0; o >>= 1) s += __shfl_xor(s, o);
    float mean = s * (1.0f/DD);
    float s2 = 0.f;
    #pragma unroll
    for (int c = 0; c < 3; c++) {
        float4 v = c == 0 ? v0 : (c == 1 ? v1 : v2);
        float dx = v.x-mean, dy = v.y-mean, dz = v.z-mean, dw = v.w-mean;
        s2 += dx*dx + dy*dy + dz*dz + dw*dw;
    }
    #pragma unroll
    for (int o = 32; o > 0; o >>= 1) s2 += __shfl_xor(s2, o);
    float rs = rsqrtf(s2 * (1.0f/DD) + 1e-5f);
    const float4* gr = (const float4*)g;
    const float4* br = (const float4*)b;
    #pragma unroll
    for (int c = 0; c < 3; c++) {
        float4 v = c == 0 ? v0 : (c == 1 ? v1 : v2);
        float4 gg = gr[lane + 64*c], bb = br[lane + 64*c];
        bf16x4 o;
        o[0] = (bf16_t)((v.x - mean) * rs * gg.x + bb.x);
        o[1] = (bf16_t)((v.y - mean) * rs * gg.y + bb.y);
        o[2] = (bf16_t)((v.z - mean) * rs * gg.z + bb.z);
        o[3] = (bf16_t)((v.w - mean) * rs * gg.w + bb.w);
        *(bf16x4*)(qn + (size_t)wid * DD + (lane + 64*c) * 4) = o;
    }
}

// ---------------- LN2 + gate: one wave per token ----------------
__global__ __launch_bounds__(256) void ln2_gate_kernel(const float* __restrict__ x,
                                                       const float* __restrict__ g,
                                                       const float* __restrict__ b,
                                                       const float* __restrict__ gw,
                                                       const float* __restrict__ gb,
                                                       bf16_t* __restrict__ yb,
                                                       float* __restrict__ gv,
                                                       int* __restrict__ cnt,
                                                       int* __restrict__ idxb)
{
    int wid = (blockIdx.x * 256 + threadIdx.x) >> 6;
    if (wid >= MT) return;
    int lane = threadIdx.x & 63;
    const float4* xr = (const float4*)(x + (size_t)wid * DD);
    float4 v0 = xr[lane], v1 = xr[lane + 64], v2 = xr[lane + 128];
    float s = v0.x+v0.y+v0.z+v0.w + v1.x+v1.y+v1.z+v1.w + v2.x+v2.y+v2.z+v2.w;
    #pragma unroll
    for (int o = 32; o > 0; o >>= 1) s += __shfl_xor(s, o);
    float mean = s * (1.0f/DD);
    float s2 = 0.f;
    #pragma unroll
    for (int c = 0; c < 3; c++) {
        float4 v = c == 0 ? v0 : (c == 1 ? v1 : v2);
        float dx = v.x-mean, dy = v.y-mean, dz = v.z-mean, dw = v.w-mean;
        s2 += dx*dx + dy*dy + dz*dz + dw*dw;
    }
    #pragma unroll
    for (int o = 32; o > 0; o >>= 1) s2 += __shfl_xor(s2, o);
    float rs = rsqrtf(s2 * (1.0f/DD) + 1e-5f);
    const float4* gr = (const float4*)g;
    const float4* br = (const float4*)b;
    float p0 = 0.f, p1 = 0.f, p2 = 0.f, p3 = 0.f;
    #pragma unroll
    for (int c = 0; c < 3; c++) {
        float4 v = c == 0 ? v0 : (c == 1 ? v1 : v2);
        float4 gg = gr[lane + 64*c], bb = br[lane + 64*c];
        float y0 = (v.x - mean) * rs * gg.x + bb.x;
        float y1 = (v.y - mean) * rs * gg.y + bb.y;
        float y2 = (v.z - mean) * rs * gg.z + bb.z;
        float y3 = (v.w - mean) * rs * gg.w + bb.w;
        bf16x4 o; o[0]=(bf16_t)y0; o[1]=(bf16_t)y1; o[2]=(bf16_t)y2; o[3]=(bf16_t)y3;
        *(bf16x4*)(yb + (size_t)wid * DD + (lane + 64*c) * 4) = o;
        int off = lane + 64*c;
        float4 w0 = ((const float4*)(gw          ))[off];
        float4 w1v = ((const float4*)(gw +   DD  ))[off];
        float4 w2v = ((const float4*)(gw + 2*DD  ))[off];
        float4 w3v = ((const float4*)(gw + 3*DD  ))[off];
        p0 += y0*w0.x + y1*w0.y + y2*w0.z + y3*w0.w;
        p1 += y0*w1v.x + y1*w1v.y + y2*w1v.z + y3*w1v.w;
        p2 += y0*w2v.x + y1*w2v.y + y2*w2v.z + y3*w2v.w;
        p3 += y0*w3v.x + y1*w3v.y + y2*w3v.z + y3*w3v.w;
    }
    #pragma unroll
    for (int o = 32; o > 0; o >>= 1) {
        p0 += __shfl_xor(p0, o); p1 += __shfl_xor(p1, o);
        p2 += __shfl_xor(p2, o); p3 += __shfl_xor(p3, o);
    }
    if (lane == 0) {
        float l0 = p0 + gb[0], l1 = p1 + gb[1], l2 = p2 + gb[2], l3 = p3 + gb[3];
        int top = 0; float best = l0;
        if (l1 > best) { best = l1; top = 1; }
        if (l2 > best) { best = l2; top = 2; }
        if (l3 > best) { best = l3; top = 3; }
        float Z = __expf(l0-best) + __expf(l1-best) + __expf(l2-best) + __expf(l3-best);
        gv[wid] = 1.0f / Z;
        int pos = atomicAdd(&cnt[top], 1);
        idxb[top * MT + pos] = wid;
    }
}

// ---------------- MFMA attention: block per (q-tile, head, batch); V from vt (pre-transposed) ----------------
__global__ __launch_bounds__(256) void attn_kernel(const bf16_t* __restrict__ qkv,
                                                   const bf16_t* __restrict__ vt,
                                                   bf16_t* __restrict__ ob)
{
    int qt = blockIdx.x, hh = blockIdx.y, b = blockIdx.z;
    __shared__ bf16_t Qs[64 * 64];
    __shared__ bf16_t KV[64 * 64];
    __shared__ float  Sc[64 * SCW];
    __shared__ float  linv[64];

    int tid = threadIdx.x, lane = tid & 63, w = tid >> 6;
    int wm = (w >> 1) * 32, wn = (w & 1) * 32;
    int fr = lane & 15, fs = lane >> 4;

    #pragma unroll
    for (int it = 0; it < 2; it++) {
        int row = 8*(it*4 + w) + (lane >> 3), cc = lane & 7;
        int q = qt*64 + row; if (q > SS-1) q = SS-1;
        const bf16_t* src = qkv + ((size_t)(b*SS + q))*QKVN + hh*64 + ((cc ^ (row & 7)) << 3);
        gload16(src, &Qs[(it*4 + w) * 512]);
    }

    for (int kt = 0; kt < 4; kt++) {
        __syncthreads();
        #pragma unroll
        for (int it = 0; it < 2; it++) {
            int row = 8*(it*4 + w) + (lane >> 3), cc = lane & 7;
            int k = kt*64 + row; if (k > SS-1) k = SS-1;
            const bf16_t* src = qkv + ((size_t)(b*SS + k))*QKVN + 768 + hh*64 + ((cc ^ (row & 7)) << 3);
            gload16(src, &KV[(it*4 + w) * 512]);
        }
        __syncthreads();
        f32x4 acc[2][2];
        #pragma unroll
        for (int mi = 0; mi < 2; mi++)
            #pragma unroll
            for (int ni = 0; ni < 2; ni++)
                #pragma unroll
                for (int j = 0; j < 4; j++) acc[mi][ni][j] = 0.f;
        #pragma unroll
        for (int ks = 0; ks < 2; ks++) {
            bf16x8 af[2], bfr[2];
            #pragma unroll
            for (int mi = 0; mi < 2; mi++) {
                int r = wm + mi * 16 + fr;
                af[mi] = *(bf16x8*)&Qs[r * 64 + (((fs + ks*4) ^ (r & 7)) << 3)];
            }
            #pragma unroll
            for (int ni = 0; ni < 2; ni++) {
                int r = wn + ni * 16 + fr;
                bfr[ni] = *(bf16x8*)&KV[r * 64 + (((fs + ks*4) ^ (r & 7)) << 3)];
            }
            #pragma unroll
            for (int mi = 0; mi < 2; mi++)
                #pragma unroll
                for (int ni = 0; ni < 2; ni++)
                    acc[mi][ni] = __builtin_amdgcn_mfma_f32_16x16x32_bf16(af[mi], bfr[ni], acc[mi][ni], 0, 0, 0);
        }
        #pragma unroll
        for (int mi = 0; mi < 2; mi++)
            #pragma unroll
            for (int j = 0; j < 4; j++) {
                int qr = wm + mi * 16 + fs * 4 + j;
                #pragma unroll
                for (int ni = 0; ni < 2; ni++) {
                    int col = kt*64 + wn + ni * 16 + fr;
                    if (col < SCW) {
                        float v = acc[mi][ni][j] * 0.125f;
                        if (col > SS-1) v = -1e30f;
                        Sc[qr * SCW + col] = v;
                    }
                }
            }
    }
    __syncthreads();

    {
        int row = tid >> 2, c = tid & 3;
        float m = -1e30f;
        for (int i = c; i < SCW; i += 4) m = fmaxf(m, Sc[row * SCW + i]);
        m = fmaxf(m, __shfl_xor(m, 1, 4));
        m = fmaxf(m, __shfl_xor(m, 2, 4));
        float s = 0.f;
        for (int i = c; i < SCW; i += 4) {
            float e = __expf(Sc[row * SCW + i] - m);
            Sc[row * SCW + i] = e;
            s += e;
        }
        s += __shfl_xor(s, 1, 4);
        s += __shfl_xor(s, 2, 4);
        if (c == 0) linv[row] = 1.0f / s;
    }

    f32x4 pv[2][2];
    #pragma unroll
    for (int mi = 0; mi < 2; mi++)
        #pragma unroll
        for (int ni = 0; ni < 2; ni++)
            #pragma unroll
            for (int j = 0; j < 4; j++) pv[mi][ni][j] = 0.f;

    const bf16_t* vbase = vt + ((size_t)(b*12 + hh) * 64) * SPAD;
    for (int kt = 0; kt < 4; kt++) {
        __syncthreads();
        #pragma unroll
        for (int it = 0; it < 2; it++) {
            int row = 8*(it*4 + w) + (lane >> 3), cc = lane & 7;   // row = d
            const bf16_t* src = vbase + (size_t)row * SPAD + kt*64 + ((cc ^ (row & 7)) << 3);
            gload16(src, &KV[(it*4 + w) * 512]);
        }
        __syncthreads();
        #pragma unroll
        for (int ks = 0; ks < 2; ks++) {
            int s0 = kt*64 + ks*32;
            if (s0 > SS-1) continue;
            bf16x8 af[2], bfr[2];
            #pragma unroll
            for (int mi = 0; mi < 2; mi++) {
                int qr = wm + mi * 16 + fr;
                const float* p = &Sc[qr * SCW + s0 + fs * 8];
                af[mi] = cvt8(*(const float4*)p, *(const float4*)(p + 4));
            }
            #pragma unroll
            for (int ni = 0; ni < 2; ni++) {
                int d = wn + ni * 16 + fr;
                bfr[ni] = *(bf16x8*)&KV[d * 64 + (((fs + ks*4) ^ (d & 7)) << 3)];
            }
            #pragma unroll
            for (int mi = 0; mi < 2; mi++)
                #pragma unroll
                for (int ni = 0; ni < 2; ni++)
                    pv[mi][ni] = __builtin_amdgcn_mfma_f32_16x16x32_bf16(af[mi], bfr[ni], pv[mi][ni], 0, 0, 0);
        }
    }

    #pragma unroll
    for (int mi = 0; mi < 2; mi++)
        #pragma unroll
        for (int j = 0; j < 4; j++) {
            int qr = wm + mi * 16 + fs * 4 + j;
            int q = qt*64 + qr;
            if (q > SS-1) continue;
            float il = linv[qr];
            #pragma unroll
            for (int ni = 0; ni < 2; ni++) {
                int d = wn + ni * 16 + fr;
                ob[((size_t)(b*SS + q))*DD + hh*64 + d] = (bf16_t)(pv[mi][ni][j] * il);
            }
        }
}

// ---------------- classifier head ----------------
__global__ void head_kernel(const float* __restrict__ h, const float* __restrict__ hw,
                            const float* __restrict__ hb, float* __restrict__ out)
{
    int i = blockIdx.x * 256 + threadIdx.x;
    if (i >= BB * 1000) return;
    int b = i & 7, n = i >> 3;
    const float4* hr = (const float4*)(h + (size_t)(b * SS) * DD);
    const float4* wr = (const float4*)(hw + (size_t)n * DD);
    float s = 0.f;
    #pragma unroll 4
    for (int k = 0; k < DD/4; k++) {
        float4 a = hr[k], wv = wr[k];
        s += a.x*wv.x + a.y*wv.y + a.z*wv.z + a.w*wv.w;
    }
    out[b * 1000 + n] = s + hb[n];
}

extern "C" void kernel_launch(void* const* d_in, const int* in_sizes, int n_in,
                              void* d_out, int out_size, void* d_ws, size_t ws_size,
                              hipStream_t stream) {
    const float* x          = (const float*)d_in[0];
    const float* patch_w    = (const float*)d_in[1];
    const float* patch_b    = (const float*)d_in[2];
    const float* cls_token  = (const float*)d_in[3];
    const float* pos_embed  = (const float*)d_in[4];
    const float* ln1_g      = (const float*)d_in[5];
    const float* ln1_b      = (const float*)d_in[6];
    const float* ln2_g      = (const float*)d_in[7];
    const float* ln2_b      = (const float*)d_in[8];
    const float* attn_in_w  = (const float*)d_in[9];
    const float* attn_in_b  = (const float*)d_in[10];
    const float* attn_out_w = (const float*)d_in[11];
    const float* attn_out_b = (const float*)d_in[12];
    const float* gate_w     = (const float*)d_in[13];
    const float* gate_b     = (const float*)d_in[14];
    const float* w1         = (const float*)d_in[15];
    const float* b1         = (const float*)d_in[16];
    const float* w2         = (const float*)d_in[17];
    const float* b2         = (const float*)d_in[18];
    const float* head_w     = (const float*)d_in[19];
    const float* head_b     = (const float*)d_in[20];
    float* out = (float*)d_out;

    char* wsb = (char*)d_ws;
    auto alloc = [&](size_t bytes) { char* p = wsb; wsb += (bytes + 63) & ~63ULL; return p; };
    bf16_t* Xp     = (bf16_t*)alloc((size_t)MPE * DD * 2);
    float*  h      = (float*) alloc((size_t)MT * DD * 4);
    bf16_t* qn_bf  = (bf16_t*)alloc((size_t)MT * DD * 2);
    bf16_t* h_bf   = (bf16_t*)alloc((size_t)MT * DD * 2);
    bf16_t* qkv_bf = (bf16_t*)alloc((size_t)MT * QKVN * 2);
    bf16_t* vt     = (bf16_t*)alloc((size_t)96 * 64 * SPAD * 2);
    bf16_t* ob_bf  = (bf16_t*)alloc((size_t)MT * DD * 2);
    bf16_t* yb_bf  = (bf16_t*)alloc((size_t)MT * DD * 2);
    bf16_t* hd_bf  = (bf16_t*)alloc((size_t)MT * HHID * 2);
    float*  gv     = (float*) alloc((size_t)MT * 4);
    int*    cnt    = (int*)   alloc(12 * NEXP * 4);
    int*    idxb   = (int*)   alloc((size_t)12 * NEXP * MT * 4);

    dim3 blk(256);
    dim3 blk512(512);
    const int NOSPLIT = 1 << 30;

    init_misc<<<24, blk, 0, stream>>>(cls_token, pos_embed, h, h_bf, cnt);
    gather_patches<<<(MPE*DD + 255)/256, blk, 0, stream>>>(x, Xp);
    // patch embed -> h rows s>=1 (bias=patch_b, pos via gv slot): 25x12 tiles
    gemm_bf16<64,64,32,32,7,0><<<dim3(300, 1, 1), blk, 0, stream>>>(
        Xp, nullptr, NOSPLIT, patch_w, patch_b, h, h_bf, nullptr, nullptr, pos_embed,
        MPE, DD, DD, 25, 12);

    for (int i = 0; i < 12; i++) {
        const float* aw    = attn_in_w  + (size_t)i * QKVN * DD;
        const float* ow    = attn_out_w + (size_t)i * DD * DD;
        const float* w1l   = w1 + (size_t)i * NEXP * DD * HHID;
        const float* w2l   = w2 + (size_t)i * NEXP * HHID * DD;
        const float* ab    = attn_in_b  + (size_t)i * QKVN;
        const float* obias = attn_out_b + (size_t)i * DD;
        const float* l1g = ln1_g + (size_t)i * DD;
        const float* l1b = ln1_b + (size_t)i * DD;
        const float* l2g = ln2_g + (size_t)i * DD;
        const float* l2b = ln2_b + (size_t)i * DD;
        const float* gw  = gate_w + (size_t)i * NEXP * DD;
        const float* gb  = gate_b + (size_t)i * NEXP;
        const float* b1l = b1 + (size_t)i * NEXP * HHID;
        const float* b2l = b2 + (size_t)i * NEXP * DD;
        int* cnt_i  = cnt  + i * NEXP;
        int* idxb_i = idxb + (size_t)i * NEXP * MT;

        ln1_kernel<<<dim3((MT*64 + 255)/256), blk, 0, stream>>>(h, l1g, l1b, qn_bf);
        // merged q|kv projection: n0 < 768 uses qn_bf, else h_bf; B = attn_in_w fp32 [2304,768]
        gemm_bf16<128,64,64,32,5,0><<<dim3(468, 1, 1), blk, 0, stream>>>(
            qn_bf, h_bf, DD, aw, ab, nullptr, qkv_bf, nullptr, nullptr, nullptr,
            MT, QKVN, DD, 13, 36);
        transpose_v<<<dim3(8, 2, 96), blk, 0, stream>>>(qkv_bf, vt);
        attn_kernel<<<dim3(4, 12, BB), blk, 0, stream>>>(qkv_bf, vt, ob_bf);
        gemm_bf16<64,64,32,32,2,0><<<dim3(300, 1, 1), blk, 0, stream>>>(
            ob_bf, nullptr, NOSPLIT, ow, obias, h, nullptr, nullptr, nullptr, nullptr,
            MT, DD, DD, 25, 12);
        ln2_gate_kernel<<<dim3((MT*64 + 255)/256), blk, 0, stream>>>(
            h, l2g, l2b, gw, gb, yb_bf, gv, cnt_i, idxb_i);
        // moe1: B = w1[i] fp32 [768,3072] per expert, transposed in-flight (TN)
        gemm_bf16<128,128,64,32,3,1><<<dim3(312, 1, NEXP), blk512, 0, stream>>>(
            yb_bf, nullptr, NOSPLIT, w1l, b1l, nullptr, hd_bf, cnt_i, idxb_i, nullptr,
            MT, HHID, DD, 13, 24);
        // moe2: B = w2[i] fp32 [3072,768] per expert (TN)
        gemm_bf16<64,64,32,32,4,1><<<dim3(300, 1, NEXP), blk, 0, stream>>>(
            hd_bf, nullptr, NOSPLIT, w2l, b2l, h, h_bf, cnt_i, idxb_i, gv,
            MT, DD, HHID, 25, 12);
    }

    head_kernel<<<(BB*1000 + 255)/256, blk, 0, stream>>>(h, head_w, head_b, out);
}